// Round 6
// baseline (170.130 us; speedup 1.0000x reference)
//
#include <hip/hip_runtime.h>
#include <hip/hip_bf16.h>
#include <cstdint>
#include <cstddef>

// ---------- types ----------
typedef __attribute__((ext_vector_type(8))) _Float16 half8;
typedef __attribute__((ext_vector_type(4))) float floatx4;

#define MFMA16(a, b, c) __builtin_amdgcn_mfma_f32_16x16x32_f16((a), (b), (c), 0, 0, 0)

// direct global->LDS DMA, 16B per lane, dest = uniform base + lane*16
#define GLOAD_LDS16(g, l)                                                     \
    __builtin_amdgcn_global_load_lds(                                         \
        (const __attribute__((address_space(1))) void*)(g),                   \
        (__attribute__((address_space(3))) void*)(l), 16, 0, 0)

// Problem constants: A=64, T=512, D=256, H=4, HD=64
#define NFEAT 8388608   // 64*512*256

// ---------- fused QKV GEMM, software-pipelined ----------
// 1D grid 512: xcd = n&7; per XCD 32 bm x 2 bn. X tile [128x256] staged once
// (fp32->fp16 inline, slab-major [ks][128][64] with XOR chunk swizzle), then
// 12 W tiles (3 weights x 4 k-slabs) pipelined: W(t+1) global->regs issued
// before tile t's MFMAs, regs->LDS after the post-MFMA barrier.
// LDS 80 KB -> 2 blocks/CU.
__global__ __launch_bounds__(256) void qkv_fused(
    const float* __restrict__ feat,
    const float* __restrict__ Wq, const float* __restrict__ Wk,
    const float* __restrict__ Wv,
    const float* __restrict__ bq, const float* __restrict__ bk,
    const float* __restrict__ bv,
    _Float16* __restrict__ Qb, _Float16* __restrict__ Kb, _Float16* __restrict__ Vb)
{
    __shared__ _Float16 Xs[4 * 128 * 64];   // 64 KB slab-major
    __shared__ _Float16 Ws[128 * 64];       // 16 KB

    const int n   = blockIdx.x;
    const int idx = n >> 3;
    const int bm  = (n & 7) * 32 + (idx >> 1);
    const int bn  = idx & 1;

    const int tid  = threadIdx.x;
    const int lane = tid & 63, wid = tid >> 6;
    const int quad = lane >> 4, l16 = lane & 15;
    const int wm = wid & 1, wn = wid >> 1;

    // ---- stage X once: 4 slabs of 64 cols, XOR swizzle within slab ----
    const float* Xg = feat + (size_t)bm * 128 * 256;
#pragma unroll
    for (int sl = 0; sl < 4; ++sl)
#pragma unroll
        for (int i = 0; i < 4; ++i) {
            int g   = tid + 256 * i;       // 1024 groups of 8 halfs per slab
            int row = g >> 3, chd = g & 7;
            int chs = chd ^ (row & 7);
            const float* s = Xg + (size_t)row * 256 + sl * 64 + chs * 8;
            float4 v0 = *(const float4*)s;
            float4 v1 = *(const float4*)(s + 4);
            half8 h = { (_Float16)v0.x, (_Float16)v0.y, (_Float16)v0.z, (_Float16)v0.w,
                        (_Float16)v1.x, (_Float16)v1.y, (_Float16)v1.z, (_Float16)v1.w };
            *(half8*)(&Xs[sl * 8192 + row * 64 + chd * 8]) = h;
        }

    // ---- W prefetch machinery: t = z*4 + ks ----
    const float* Wz[3] = { Wq, Wk, Wv };
    const float* bz[3] = { bq, bk, bv };
    _Float16*    oz[3] = { Qb, Kb, Vb };

    int wrow[4], wchd[4];
#pragma unroll
    for (int i = 0; i < 4; ++i) {
        int g = tid + 256 * i;
        wrow[i] = g >> 3;
        wchd[i] = g & 7;
    }
    float4 pv0[4], pv1[4];

    auto loadW = [&](int t) {
        const float* base = Wz[t >> 2] + (size_t)bn * 32768 + (t & 3) * 64;
#pragma unroll
        for (int i = 0; i < 4; ++i) {
            int chs = wchd[i] ^ (wrow[i] & 7);
            const float* s = base + (size_t)wrow[i] * 256 + chs * 8;
            pv0[i] = *(const float4*)s;
            pv1[i] = *(const float4*)(s + 4);
        }
    };
    auto storeW = [&]() {
#pragma unroll
        for (int i = 0; i < 4; ++i) {
            half8 h = { (_Float16)pv0[i].x, (_Float16)pv0[i].y,
                        (_Float16)pv0[i].z, (_Float16)pv0[i].w,
                        (_Float16)pv1[i].x, (_Float16)pv1[i].y,
                        (_Float16)pv1[i].z, (_Float16)pv1[i].w };
            *(half8*)(&Ws[wrow[i] * 64 + wchd[i] * 8]) = h;
        }
    };

    loadW(0);
    storeW();
    floatx4 acc[4][4] = {};

#pragma unroll 1
    for (int t = 0; t < 12; ++t) {
        __syncthreads();               // Ws (and Xs at t=0) visible
        if (t < 11) loadW(t + 1);      // issue early; latency hides under MFMAs
        const int ks = t & 3;
#pragma unroll
        for (int kh = 0; kh < 2; ++kh) {
            half8 af[4], bf[4];
#pragma unroll
            for (int mi = 0; mi < 4; ++mi) {
                int row = wm * 64 + mi * 16 + l16;
                int cs  = (kh * 4 + quad) ^ (row & 7);
                af[mi] = *(const half8*)(&Xs[ks * 8192 + row * 64 + cs * 8]);
            }
#pragma unroll
            for (int ni = 0; ni < 4; ++ni) {
                int row = wn * 64 + ni * 16 + l16;
                int cs  = (kh * 4 + quad) ^ (row & 7);
                bf[ni] = *(const half8*)(&Ws[row * 64 + cs * 8]);
            }
#pragma unroll
            for (int mi = 0; mi < 4; ++mi)
#pragma unroll
                for (int ni = 0; ni < 4; ++ni)
                    acc[mi][ni] = MFMA16(af[mi], bf[ni], acc[mi][ni]);
        }
        __syncthreads();               // all Ws reads done
        if (t < 11) storeW();
        if ((t & 3) == 3) {
            // epilogue for z = t>>2; C/D: col = lane&15, row = quad*4 + r
            const int z = t >> 2;
            const float* bias = bz[z];
            _Float16*    outp = oz[z];
#pragma unroll
            for (int ni = 0; ni < 4; ++ni) {
                int col = bn * 128 + wn * 64 + ni * 16 + l16;
                float bv2 = bias[col];
#pragma unroll
                for (int mi = 0; mi < 4; ++mi) {
#pragma unroll
                    for (int r = 0; r < 4; ++r) {
                        int row = bm * 128 + wm * 64 + mi * 16 + quad * 4 + r;
                        outp[(size_t)row * 256 + col] =
                            (_Float16)(acc[mi][ni][r] + bv2);
                    }
                    acc[mi][ni] = floatx4{0.f, 0.f, 0.f, 0.f};
                }
            }
        }
    }
}

// ---------- out GEMM, same pipelined shape (1 z, A fp16 via DMA) ----------
__global__ __launch_bounds__(256) void out_gemm(
    const _Float16* __restrict__ attnH, const float* __restrict__ Wo,
    const float* __restrict__ bo, float* __restrict__ out)
{
    __shared__ _Float16 Xs[4 * 128 * 64];   // 64 KB slab-major
    __shared__ _Float16 Ws[128 * 64];       // 16 KB

    const int n   = blockIdx.x;
    const int idx = n >> 3;
    const int bm  = (n & 7) * 32 + (idx >> 1);
    const int bn  = idx & 1;

    const int tid  = threadIdx.x;
    const int lane = tid & 63, wid = tid >> 6;
    const int quad = lane >> 4, l16 = lane & 15;
    const int wm = wid & 1, wn = wid >> 1;

    // ---- stage whole A tile [128][256] via DMA, slab-major, XOR swizzle ----
    const _Float16* Ag = attnH + (size_t)bm * 128 * 256;
#pragma unroll
    for (int sl = 0; sl < 4; ++sl)
#pragma unroll
        for (int i = 0; i < 4; ++i) {
            int grp = wid * 4 + i;          // 16 groups of 8 rows per slab
            int row = grp * 8 + (lane >> 3);
            int sc  = (lane & 7) ^ (row & 7);
            GLOAD_LDS16(Ag + (size_t)row * 256 + sl * 64 + sc * 8,
                        Xs + sl * 8192 + grp * 512);
        }

    int wrow[4], wchd[4];
#pragma unroll
    for (int i = 0; i < 4; ++i) {
        int g = tid + 256 * i;
        wrow[i] = g >> 3;
        wchd[i] = g & 7;
    }
    float4 pv0[4], pv1[4];

    auto loadW = [&](int t) {
        const float* base = Wo + (size_t)bn * 32768 + t * 64;
#pragma unroll
        for (int i = 0; i < 4; ++i) {
            int chs = wchd[i] ^ (wrow[i] & 7);
            const float* s = base + (size_t)wrow[i] * 256 + chs * 8;
            pv0[i] = *(const float4*)s;
            pv1[i] = *(const float4*)(s + 4);
        }
    };
    auto storeW = [&]() {
#pragma unroll
        for (int i = 0; i < 4; ++i) {
            half8 h = { (_Float16)pv0[i].x, (_Float16)pv0[i].y,
                        (_Float16)pv0[i].z, (_Float16)pv0[i].w,
                        (_Float16)pv1[i].x, (_Float16)pv1[i].y,
                        (_Float16)pv1[i].z, (_Float16)pv1[i].w };
            *(half8*)(&Ws[wrow[i] * 64 + wchd[i] * 8]) = h;
        }
    };

    loadW(0);
    storeW();
    floatx4 acc[4][4] = {};

#pragma unroll 1
    for (int t = 0; t < 4; ++t) {
        __syncthreads();               // Ws + A DMA visible (vmcnt drain)
        if (t < 3) loadW(t + 1);
#pragma unroll
        for (int kh = 0; kh < 2; ++kh) {
            half8 af[4], bf[4];
#pragma unroll
            for (int mi = 0; mi < 4; ++mi) {
                int row = wm * 64 + mi * 16 + l16;
                int cs  = (kh * 4 + quad) ^ (row & 7);
                af[mi] = *(const half8*)(&Xs[t * 8192 + row * 64 + cs * 8]);
            }
#pragma unroll
            for (int ni = 0; ni < 4; ++ni) {
                int row = wn * 64 + ni * 16 + l16;
                int cs  = (kh * 4 + quad) ^ (row & 7);
                bf[ni] = *(const half8*)(&Ws[row * 64 + cs * 8]);
            }
#pragma unroll
            for (int mi = 0; mi < 4; ++mi)
#pragma unroll
                for (int ni = 0; ni < 4; ++ni)
                    acc[mi][ni] = MFMA16(af[mi], bf[ni], acc[mi][ni]);
        }
        __syncthreads();
        if (t < 3) storeW();
    }

#pragma unroll
    for (int ni = 0; ni < 4; ++ni) {
        int col = bn * 128 + wn * 64 + ni * 16 + l16;
        float bv = bo[col];
#pragma unroll
        for (int mi = 0; mi < 4; ++mi)
#pragma unroll
            for (int r = 0; r < 4; ++r) {
                int row = bm * 128 + wm * 64 + mi * 16 + quad * 4 + r;
                out[(size_t)row * 256 + col] = acc[mi][ni][r] + bv;
            }
    }
}

// ---------- banded sparse attention (unchanged from R5) ----------
__global__ __launch_bounds__(256) void attn_kernel(
    const _Float16* __restrict__ Qb, const _Float16* __restrict__ Kb,
    const _Float16* __restrict__ Vb, const float* __restrict__ positions,
    const int* __restrict__ mdp, const int* __restrict__ twp,
    _Float16* __restrict__ attnb)
{
    const int n   = blockIdx.x;
    const int idx = n >> 3;
    const int a   = (n & 7) * 8 + (idx >> 5);
    const int rem = idx & 31;
    const int qt  = rem >> 2, h = rem & 3;

    const int q0 = qt * 64;
    const int s_base = q0 - 64;
    const int tid = threadIdx.x, lane = tid & 63, wid = tid >> 6;
    const int quad = lane >> 4, l16 = lane & 15;

    __shared__ _Float16 KPs[192 * 64];   // packed K (XOR), reused as packed P
    __shared__ _Float16 Vt[64 * 192];    // packed V^T (XOR chunk swizzle)

    const size_t abase = (size_t)a * 512;
    const int md = *mdp, tw = *twp;
    const float md2 = (float)(md * md);

    const size_t qrow = abase + q0 + wid * 16 + l16;
    half8 aq0 = *(const half8*)(Qb + qrow * 256 + h * 64 + quad * 8);
    half8 aq1 = *(const half8*)(Qb + qrow * 256 + h * 64 + 32 + quad * 8);
    float qpx[4], qpy[4];
    int trow[4];
#pragma unroll
    for (int r = 0; r < 4; ++r) {
        int m = wid * 16 + quad * 4 + r;
        trow[r] = q0 + m;
        float2 qp = *(const float2*)(positions + (abase + q0 + m) * 2);
        qpx[r] = qp.x;
        qpy[r] = qp.y;
    }

#pragma unroll
    for (int i = 0; i < 6; ++i) {
        int grp = wid * 6 + i;
        int si  = grp * 8 + (lane >> 3);
        int sc  = min(max(s_base + si, 0), 511);
        int ch  = (lane & 7) ^ (si & 7);
        GLOAD_LDS16(Kb + (abase + sc) * 256 + h * 64 + ch * 8, KPs + grp * 512);
    }
#pragma unroll
    for (int i = 0; i < 3; ++i) {
        int g   = tid + 256 * i;
        int si2 = (g % 96) * 2;
        int d0  = (g / 96) * 8;
        int sa  = min(max(s_base + si2, 0), 511);
        int sb  = min(max(s_base + si2 + 1, 0), 511);
        half8 v0 = *(const half8*)(Vb + (abase + sa) * 256 + h * 64 + d0);
        half8 v1 = *(const half8*)(Vb + (abase + sb) * 256 + h * 64 + d0);
        int c = si2 >> 3;
#pragma unroll
        for (int j = 0; j < 8; ++j) {
            int d  = d0 + j;
            int cs = (c & ~7) | ((c & 7) ^ (d & 7));
            union { _Float16 hh[2]; uint32_t u; } p;
            p.hh[0] = v0[j]; p.hh[1] = v1[j];
            *(uint32_t*)(&Vt[d * 192 + cs * 8 + (si2 & 7)]) = p.u;
        }
    }
    __syncthreads();

    floatx4 S[12];
#pragma unroll
    for (int j = 0; j < 12; ++j) {
        int si = j * 16 + l16;
        half8 bk0 = *(const half8*)(&KPs[si * 64 + ((quad) ^ (si & 7)) * 8]);
        half8 bk1 = *(const half8*)(&KPs[si * 64 + ((4 + quad) ^ (si & 7)) * 8]);
        floatx4 acc = {};
        acc = MFMA16(aq0, bk0, acc);
        acc = MFMA16(aq1, bk1, acc);
        int sr = s_base + si;
        int sc = min(max(sr, 0), 511);
        float2 kp = *(const float2*)(positions + (abase + sc) * 2);
        bool svalid = (sr >= 0) && (sr < 512);
#pragma unroll
        for (int r = 0; r < 4; ++r) {
            float dx = qpx[r] - kp.x, dy = qpy[r] - kp.y;
            float d2 = dx * dx + dy * dy;
            int dt = trow[r] - sr; dt = dt < 0 ? -dt : dt;
            bool ok = svalid && (d2 <= md2) && (dt <= tw);
            S[j][r] = ok ? acc[r] * 0.125f : -1e30f;
        }
    }

    float minv[4];
#pragma unroll
    for (int r = 0; r < 4; ++r) {
        float m = -1e30f;
#pragma unroll
        for (int j = 0; j < 12; ++j) m = fmaxf(m, S[j][r]);
        m = fmaxf(m, __shfl_xor(m, 1));
        m = fmaxf(m, __shfl_xor(m, 2));
        m = fmaxf(m, __shfl_xor(m, 4));
        m = fmaxf(m, __shfl_xor(m, 8));
        float l = 0.f;
#pragma unroll
        for (int j = 0; j < 12; ++j) {
            float p = __expf(S[j][r] - m);
            S[j][r] = p;
            l += p;
        }
        l += __shfl_xor(l, 1);
        l += __shfl_xor(l, 2);
        l += __shfl_xor(l, 4);
        l += __shfl_xor(l, 8);
        minv[r] = 1.0f / l;
    }

    __syncthreads();

    _Float16* Ps = KPs + wid * (16 * 192);
#pragma unroll
    for (int j = 0; j < 12; ++j)
#pragma unroll
        for (int r = 0; r < 4; ++r) {
            int row = quad * 4 + r;
            int col = j * 16 + l16;
            int ch  = (col >> 3) ^ (row & 7);
            Ps[row * 192 + ch * 8 + (col & 7)] = (_Float16)(S[j][r] * minv[r]);
        }

    half8 af[6];
#pragma unroll
    for (int k = 0; k < 6; ++k) {
        int ch = (k * 4 + quad) ^ (l16 & 7);
        af[k] = *(const half8*)(&Ps[l16 * 192 + ch * 8]);
    }
#pragma unroll
    for (int nn = 0; nn < 4; ++nn) {
        floatx4 accO = {};
#pragma unroll
        for (int k = 0; k < 6; ++k) {
            int row = nn * 16 + l16;
            int c   = k * 4 + quad;
            int cs  = (c & ~7) | ((c & 7) ^ (row & 7));
            half8 bv = *(const half8*)(&Vt[row * 192 + cs * 8]);
            accO = MFMA16(af[k], bv, accO);
        }
#pragma unroll
        for (int r = 0; r < 4; ++r) {
            int row = q0 + wid * 16 + quad * 4 + r;
            attnb[(abase + row) * 256 + h * 64 + nn * 16 + l16] = (_Float16)accO[r];
        }
    }
}

// ---------- launch ----------
extern "C" void kernel_launch(void* const* d_in, const int* in_sizes, int n_in,
                              void* d_out, int out_size, void* d_ws, size_t ws_size,
                              hipStream_t stream)
{
    const float* feat = (const float*)d_in[0];
    const float* pos  = (const float*)d_in[1];
    const float* Wq   = (const float*)d_in[2];
    const float* bq   = (const float*)d_in[3];
    const float* Wk   = (const float*)d_in[4];
    const float* bk   = (const float*)d_in[5];
    const float* Wv   = (const float*)d_in[6];
    const float* bv   = (const float*)d_in[7];
    const float* Wo   = (const float*)d_in[8];
    const float* bo   = (const float*)d_in[9];
    const int*   md   = (const int*)d_in[10];
    const int*   tw   = (const int*)d_in[11];
    float*       out  = (float*)d_out;

    _Float16* ws    = (_Float16*)d_ws;
    _Float16* Qb    = ws;
    _Float16* Kb    = Qb + NFEAT;
    _Float16* Vb    = Kb + NFEAT;
    _Float16* attnH = Vb + NFEAT;      // 64 MB of d_ws

    qkv_fused<<<512, 256, 0, stream>>>(feat, Wq, Wk, Wv, bq, bk, bv, Qb, Kb, Vb);

    attn_kernel<<<2048, 256, 0, stream>>>(Qb, Kb, Vb, pos, md, tw, attnH);

    out_gemm<<<512, 256, 0, stream>>>(attnH, Wo, bo, out);
}